// Round 4
// baseline (208.722 us; speedup 1.0000x reference)
//
#include <hip/hip_runtime.h>
#include <math.h>

#define B_ 2
#define L_ 1024
#define D_ 512
#define NROW 2048
#define RS 288                  // R stride: key16|query16|g1 256
#define PI_F 3.14159274f
#define TWO_PI_F 6.28318548f

typedef __attribute__((ext_vector_type(8))) short bf16x8;
typedef __attribute__((ext_vector_type(4))) float f32x4;

__device__ __forceinline__ unsigned short f2bf(float f) {
    unsigned u = __float_as_uint(f);
    unsigned r = (u + 0x7FFFu + ((u >> 16) & 1u)) >> 16;
    return (unsigned short)r;
}
__device__ __forceinline__ float bf2f(unsigned short h) {
    return __uint_as_float((unsigned)h << 16);
}
__device__ __forceinline__ unsigned pack2(float a, float b) {
    return (unsigned)f2bf(a) | ((unsigned)f2bf(b) << 16);
}

// ---------------- GEMM1 (MFMA): R[2048][288] = x @ Wkqg^T, V -> Vthi/Vtlo transposed ----------------
// Weights read fp32 + cast inline (no prep kernel). V region written transposed hi/lo bf16.
__global__ __launch_bounds__(256) void k_gemm1v(
    const float* __restrict__ x,
    const float* __restrict__ keyw, const float* __restrict__ qryw,
    const float* __restrict__ g1w, const float* __restrict__ vw,
    const float* __restrict__ g1b, const float* __restrict__ vb,
    float* __restrict__ R,
    unsigned short* __restrict__ Vthi, unsigned short* __restrict__ Vtlo)
{
    __shared__ unsigned short As[64 * 32];
    __shared__ unsigned short Bs[128 * 32];
    const int tid = threadIdx.x;
    const int w = tid >> 6;
    const int lane = tid & 63;
    const int m0 = blockIdx.y * 64;
    const int n0 = blockIdx.x * 128;
    const int srow = tid >> 2;          // 0..63
    const int scol = (tid & 3) * 8;     // 0,8,16,24
    const int quad = lane >> 4, r16 = lane & 15;

    // B-source resolution (once per thread): this thread stages column n_, k-half th
    const int tn = tid & 127;
    const int th = tid >> 7;            // 0..1
    const int n_ = n0 + tn;
    const float* src = nullptr; int stride = 0, col = 0;
    if (n_ < 16)       { src = keyw; stride = 16;  col = n_; }
    else if (n_ < 32)  { src = qryw; stride = 16;  col = n_ - 16; }
    else if (n_ < 288) { src = g1w;  stride = 256; col = n_ - 32; }
    else if (n_ < 800) { src = vw;   stride = 512; col = n_ - 288; }

    f32x4 acc[4][2];
    #pragma unroll
    for (int mt = 0; mt < 4; ++mt)
        #pragma unroll
        for (int nt = 0; nt < 2; ++nt)
            acc[mt][nt] = (f32x4){0.f, 0.f, 0.f, 0.f};

    const float* ap = x + (size_t)(m0 + srow) * 512 + scol;

    for (int k0 = 0; k0 < 512; k0 += 32) {
        float4 a0 = *(const float4*)(ap + k0);
        float4 a1 = *(const float4*)(ap + k0 + 4);
        int4 av;
        av.x = (int)f2bf(a0.x) | ((int)f2bf(a0.y) << 16);
        av.y = (int)f2bf(a0.z) | ((int)f2bf(a0.w) << 16);
        av.z = (int)f2bf(a1.x) | ((int)f2bf(a1.y) << 16);
        av.w = (int)f2bf(a1.z) | ((int)f2bf(a1.w) << 16);
        unsigned short bvals[16];
        #pragma unroll
        for (int kk = 0; kk < 16; ++kk) {
            float v = src ? src[(size_t)(k0 + th * 16 + kk) * stride + col] : 0.f;
            bvals[kk] = f2bf(v);
        }
        __syncthreads();
        *(int4*)&As[srow * 32 + scol] = av;
        *(int4*)&Bs[tn * 32 + th * 16]     = *(int4*)&bvals[0];
        *(int4*)&Bs[tn * 32 + th * 16 + 8] = *(int4*)&bvals[8];
        __syncthreads();
        bf16x8 af[4], bfr[2];
        #pragma unroll
        for (int mt = 0; mt < 4; ++mt)
            af[mt] = *(const bf16x8*)&As[(mt * 16 + r16) * 32 + quad * 8];
        #pragma unroll
        for (int nt = 0; nt < 2; ++nt)
            bfr[nt] = *(const bf16x8*)&Bs[(w * 32 + nt * 16 + r16) * 32 + quad * 8];
        #pragma unroll
        for (int mt = 0; mt < 4; ++mt)
            #pragma unroll
            for (int nt = 0; nt < 2; ++nt)
                acc[mt][nt] = __builtin_amdgcn_mfma_f32_16x16x32_bf16(
                    af[mt], bfr[nt], acc[mt][nt], 0, 0, 0);
    }

    #pragma unroll
    for (int mt = 0; mt < 4; ++mt) {
        #pragma unroll
        for (int nt = 0; nt < 2; ++nt) {
            const int n = n0 + w * 32 + nt * 16 + r16;
            if (n < 288) {
                float bias = (n >= 32) ? g1b[n - 32] : 0.f;
                #pragma unroll
                for (int i = 0; i < 4; ++i) {
                    const int m = m0 + mt * 16 + quad * 4 + i;
                    R[(size_t)m * RS + n] = acc[mt][nt][i] + bias;
                }
            } else if (n < 800) {
                const int d = n - 288;
                const float bias = vb[d];
                ushort4 h4, l4;
                #pragma unroll
                for (int i = 0; i < 4; ++i) {
                    float v = acc[mt][nt][i] + bias;
                    unsigned short hi = f2bf(v);
                    ((unsigned short*)&h4)[i] = hi;
                    ((unsigned short*)&l4)[i] = f2bf(v - bf2f(hi));
                }
                const size_t vo = (size_t)d * 2048 + m0 + mt * 16 + quad * 4;
                *(ushort4*)&Vthi[vo] = h4;
                *(ushort4*)&Vtlo[vo] = l4;
            }
        }
    }
}

// ---------------- phasors, jk/jq, gate (4 rows/block, wave=row) ----------------
__global__ __launch_bounds__(256) void k_phasor(
    const float* __restrict__ R,
    const float* __restrict__ g2w, const float* __restrict__ g2b,
    float* __restrict__ scal)
{
    const int row = blockIdx.x * 4 + (threadIdx.x >> 6);
    const int lane = threadIdx.x & 63;
    float* sc = scal + (size_t)row * 128;
    const float* r = R + (size_t)row * RS;

    float part = 0.f;
    #pragma unroll
    for (int j = 0; j < 4; ++j) {
        float v = r[32 + lane * 4 + j];
        float h = 0.5f * v * (1.0f + erff(v * 0.70710678f));
        part += h * g2w[lane * 4 + j];
    }
    #pragma unroll
    for (int off = 32; off > 0; off >>= 1) part += __shfl_down(part, off, 64);
    if (lane == 0) sc[112] = 1.0f / (1.0f + expf(-(part + g2b[0])));

    float pr = 1.f, pim = 0.f;
    if (lane < 32) {
        float a = tanhf(r[lane]) * PI_F;
        float sv, cv;
        sincosf(a, &sv, &cv);
        int t = lane & 15;
        if (lane < 16) { sc[t] = cv; sc[16 + t] = sv; }
        else           { sc[32 + t] = cv; sc[48 + t] = sv; }
        pr = cv; pim = sv;
    }
    #pragma unroll
    for (int m = 4; m <= 8; m <<= 1) {
        float orr = __shfl_xor(pr, m, 64);
        float oii = __shfl_xor(pim, m, 64);
        float nr = pr * orr - pim * oii;
        float ni = pr * oii + pim * orr;
        pr = nr; pim = ni;
    }
    if (lane < 4)                     { sc[64 + lane] = pr; sc[68 + lane] = pim; }
    else if (lane >= 16 && lane < 20) { sc[72 + lane - 16] = pr; sc[76 + lane - 16] = pim; }
}

// ---------------- wg scan + surprise gate + Qf/Kf build + gtab ----------------
__global__ __launch_bounds__(1024) void k_wg2(
    const float* __restrict__ scal, const float* __restrict__ pf,
    const float* __restrict__ res_scale, const float* __restrict__ res_thr,
    const float* __restrict__ sur_scale, const float* __restrict__ sur_bias,
    const float* __restrict__ setw,
    float* __restrict__ gtab,
    unsigned short* __restrict__ Qf, unsigned short* __restrict__ Kf)
{
    const int b = blockIdx.x;
    const int l = threadIdx.x;
    if (b == B_) {
        float g = 0.f;
        #pragma unroll
        for (int p = 0; p < 16; ++p)
            g += cosf(TWO_PI_F * (float)l * pf[p]);
        gtab[l] = g;
        return;
    }
    const size_t row = (size_t)(b * L_ + l) * 128;
    float v[8], own[8];
    #pragma unroll
    for (int c2 = 0; c2 < 8; ++c2) { v[c2] = scal[row + 64 + c2]; own[c2] = v[c2]; }
    const int lane = l & 63;
    const int wave = l >> 6;
    #pragma unroll
    for (int off = 1; off < 64; off <<= 1) {
        float o[8];
        #pragma unroll
        for (int c2 = 0; c2 < 8; ++c2) o[c2] = __shfl_up(v[c2], off, 64);
        if (lane >= off) {
            #pragma unroll
            for (int c2 = 0; c2 < 8; ++c2) v[c2] += o[c2];
        }
    }
    __shared__ float wtot[16][8];
    if (lane == 63) {
        #pragma unroll
        for (int c2 = 0; c2 < 8; ++c2) wtot[wave][c2] = v[c2];
    }
    __syncthreads();
    float pre[8] = {0,0,0,0,0,0,0,0};
    for (int w2 = 0; w2 < wave; ++w2) {
        #pragma unroll
        for (int c2 = 0; c2 < 8; ++c2) pre[c2] += wtot[w2][c2];
    }
    float km[8];
    #pragma unroll
    for (int c2 = 0; c2 < 8; ++c2) km[c2] = pre[c2] + v[c2] - own[c2];
    float mag = 0.f;
    #pragma unroll
    for (int pp = 0; pp < 4; ++pp) {
        float jqr = scal[row + 72 + pp], jqi = scal[row + 76 + pp];
        float re = km[pp] * jqr + km[4 + pp] * jqi;
        float im = km[4 + pp] * jqr - km[pp] * jqi;
        mag += sqrtf(re * re + im * im);
    }
    mag *= 0.25f;
    float posn = fmaxf((float)l, 1.0f);
    float nres = mag / sqrtf(posn);
    float scl = fminf(fmaxf(res_scale[0], 1.0f), 20.0f);
    float thr = fminf(fmaxf(res_thr[0], 0.1f), 0.9f);
    float sur = 0.5f * (1.0f - tanhf(scl * (nres - thr)));
    float wgv = 1.0f / (1.0f + expf(-(sur_scale[0] * (sur - 0.5f) + sur_bias[0])));

    // ---- build Qf/Kf row (rank-40 factors, 64-wide padded) ----
    const float gate = scal[row + 112];
    float s0 = setw[0], s1 = setw[1], s2 = setw[2], s3 = setw[3];
    float mx = fmaxf(fmaxf(s0, s1), fmaxf(s2, s3));
    float e0 = expf(s0 - mx), e1 = expf(s1 - mx), e2 = expf(s2 - mx), e3 = expf(s3 - mx);
    float esum = e0 + e1 + e2 + e3;
    float w4[4] = {e0 / esum, e1 / esum, e2 / esum, e3 / esum};
    const float qs = 0.2f * gate;

    unsigned* qp = (unsigned*)(Qf + (size_t)(b * L_ + l) * 64);
    unsigned* kp = (unsigned*)(Kf + (size_t)(b * L_ + l) * 64);
    #pragma unroll
    for (int s = 0; s < 16; ++s) {
        float wgrp = w4[s >> 2];
        qp[s] = pack2(qs * wgrp * scal[row + 32 + s], qs * wgrp * scal[row + 48 + s]);
        kp[s] = pack2(wgv * scal[row + s], wgv * scal[row + 16 + s]);
    }
    #pragma unroll
    for (int p = 0; p < 4; ++p) {
        qp[16 + p] = pack2(qs * scal[row + 72 + p], qs * scal[row + 76 + p]);
        kp[16 + p] = pack2(wgv * scal[row + 64 + p], wgv * scal[row + 68 + p]);
    }
    #pragma unroll
    for (int s = 20; s < 32; ++s) { qp[s] = 0u; kp[s] = 0u; }
}

// ---------------- build A (tril 64x64 tiles): A = Qf@Kf^T + toeplitz, bf16 hi/lo ----------------
__global__ __launch_bounds__(256) void k_buildA(
    const unsigned short* __restrict__ Qf, const unsigned short* __restrict__ Kf,
    const float* __restrict__ scal, const float* __restrict__ gtab,
    const float* __restrict__ posw,
    unsigned short* __restrict__ Ahi, unsigned short* __restrict__ Alo,
    float* __restrict__ rowsum)
{
    const int bx = blockIdx.x;
    const int tid = threadIdx.x;
    if (bx < 16) rowsum[(bx << 8) + tid] = 0.f;   // zero 4096 floats for k_av2/k_gemm_out2

    const int b = bx / 136;
    const int r = bx % 136;
    int ti = 0;
    while ((ti + 1) * (ti + 2) / 2 <= r) ++ti;
    const int tj = r - ti * (ti + 1) / 2;

    __shared__ unsigned short Qs[64 * 72];
    __shared__ unsigned short Ks[64 * 72];
    const int srow = tid >> 2;
    const int sc16 = (tid & 3) * 16;
    {
        const unsigned short* qsrc = Qf + ((size_t)(b * L_ + ti * 64 + srow)) * 64 + sc16;
        const unsigned short* ksrc = Kf + ((size_t)(b * L_ + tj * 64 + srow)) * 64 + sc16;
        *(int4*)&Qs[srow * 72 + sc16]     = *(const int4*)(qsrc);
        *(int4*)&Qs[srow * 72 + sc16 + 8] = *(const int4*)(qsrc + 8);
        *(int4*)&Ks[srow * 72 + sc16]     = *(const int4*)(ksrc);
        *(int4*)&Ks[srow * 72 + sc16 + 8] = *(const int4*)(ksrc + 8);
    }
    __syncthreads();

    const int w = tid >> 6;
    const int lane = tid & 63;
    const int quad = lane >> 4, r16 = lane & 15;
    f32x4 acc[4];
    #pragma unroll
    for (int mt = 0; mt < 4; ++mt) acc[mt] = (f32x4){0.f, 0.f, 0.f, 0.f};
    #pragma unroll
    for (int kk = 0; kk < 2; ++kk) {
        bf16x8 bfr = *(const bf16x8*)&Ks[(w * 16 + r16) * 72 + kk * 32 + quad * 8];
        #pragma unroll
        for (int mt = 0; mt < 4; ++mt) {
            bf16x8 af = *(const bf16x8*)&Qs[(mt * 16 + r16) * 72 + kk * 32 + quad * 8];
            acc[mt] = __builtin_amdgcn_mfma_f32_16x16x32_bf16(af, bfr, acc[mt], 0, 0, 0);
        }
    }
    const float sw = 1.0f / (1.0f + expf(-posw[0]));
    const int lp = tj * 64 + w * 16 + r16;
    #pragma unroll
    for (int mt = 0; mt < 4; ++mt) {
        #pragma unroll
        for (int i = 0; i < 4; ++i) {
            const int l = ti * 64 + mt * 16 + quad * 4 + i;
            const int dl = l - lp;
            float v = 0.f;
            if (dl >= 0) {
                float gate = scal[((size_t)(b * L_ + l)) * 128 + 112];
                v = acc[mt][i] + (1.0f - gate) * sw * gtab[dl];
            }
            unsigned short hi = f2bf(v);
            unsigned short lo = f2bf(v - bf2f(hi));
            const size_t off = ((size_t)(b * L_ + l)) * 1024 + lp;
            Ahi[off] = hi;
            Alo[off] = lo;
        }
    }
}

// ---------------- AV GEMM (masked, hi/lo, 3 products) + per-row LN sums ----------------
__global__ __launch_bounds__(256) void k_av2(
    const unsigned short* __restrict__ Ahi, const unsigned short* __restrict__ Alo,
    const unsigned short* __restrict__ Vthi, const unsigned short* __restrict__ Vtlo,
    float* __restrict__ loc, float* __restrict__ rowsum)
{
    const int bx = blockIdx.x;
    const int b = bx >> 7;
    const int ti = (bx >> 3) & 15;      // l tile
    const int nj = bx & 7;              // d tile
    const int m0 = ti * 64, n0 = nj * 64;
    const int kmax = (ti + 1) * 64;

    __shared__ unsigned short Ash[64 * 32];
    __shared__ unsigned short Asl[64 * 32];
    __shared__ unsigned short Bsh[64 * 32];
    __shared__ unsigned short Bsl[64 * 32];
    __shared__ float redS[4][64];
    __shared__ float redQ[4][64];
    const int tid = threadIdx.x;
    const int w = tid >> 6;
    const int lane = tid & 63;
    const int srow = tid >> 2;
    const int scol = (tid & 3) * 8;
    const int quad = lane >> 4, r16 = lane & 15;

    f32x4 acc[4];
    #pragma unroll
    for (int mt = 0; mt < 4; ++mt) acc[mt] = (f32x4){0.f, 0.f, 0.f, 0.f};

    const unsigned short* aph = Ahi + ((size_t)(b * L_ + m0 + srow)) * 1024 + scol;
    const unsigned short* apl = Alo + ((size_t)(b * L_ + m0 + srow)) * 1024 + scol;
    const unsigned short* bph = Vthi + (size_t)(n0 + srow) * 2048 + b * L_ + scol;
    const unsigned short* bpl = Vtlo + (size_t)(n0 + srow) * 2048 + b * L_ + scol;

    for (int k0 = 0; k0 < kmax; k0 += 32) {
        int4 ah = *(const int4*)(aph + k0);
        int4 al = *(const int4*)(apl + k0);
        int4 bh = *(const int4*)(bph + k0);
        int4 bl = *(const int4*)(bpl + k0);
        __syncthreads();
        *(int4*)&Ash[srow * 32 + scol] = ah;
        *(int4*)&Asl[srow * 32 + scol] = al;
        *(int4*)&Bsh[srow * 32 + scol] = bh;
        *(int4*)&Bsl[srow * 32 + scol] = bl;
        __syncthreads();
        bf16x8 bh8 = *(const bf16x8*)&Bsh[(w * 16 + r16) * 32 + quad * 8];
        bf16x8 bl8 = *(const bf16x8*)&Bsl[(w * 16 + r16) * 32 + quad * 8];
        #pragma unroll
        for (int mt = 0; mt < 4; ++mt) {
            bf16x8 ah8 = *(const bf16x8*)&Ash[(mt * 16 + r16) * 32 + quad * 8];
            bf16x8 al8 = *(const bf16x8*)&Asl[(mt * 16 + r16) * 32 + quad * 8];
            acc[mt] = __builtin_amdgcn_mfma_f32_16x16x32_bf16(ah8, bh8, acc[mt], 0, 0, 0);
            acc[mt] = __builtin_amdgcn_mfma_f32_16x16x32_bf16(ah8, bl8, acc[mt], 0, 0, 0);
            acc[mt] = __builtin_amdgcn_mfma_f32_16x16x32_bf16(al8, bh8, acc[mt], 0, 0, 0);
        }
    }
    const int n = n0 + w * 16 + r16;
    #pragma unroll
    for (int mt = 0; mt < 4; ++mt) {
        #pragma unroll
        for (int i = 0; i < 4; ++i) {
            const int m = m0 + mt * 16 + quad * 4 + i;
            loc[((size_t)(b * L_ + m)) * 512 + n] = acc[mt][i];
            // row-sum reduce over the 16 n-lanes of this quad group
            float s = acc[mt][i], s2 = s * s;
            #pragma unroll
            for (int off = 8; off > 0; off >>= 1) {
                s  += __shfl_xor(s, off, 16);
                s2 += __shfl_xor(s2, off, 16);
            }
            if (r16 == 0) {
                redS[w][mt * 16 + quad * 4 + i] = s;
                redQ[w][mt * 16 + quad * 4 + i] = s2;
            }
        }
    }
    __syncthreads();
    if (tid < 64)
        atomicAdd(&rowsum[(size_t)b * L_ + m0 + tid],
                  redS[0][tid] + redS[1][tid] + redS[2][tid] + redS[3][tid]);
    else if (tid < 128) {
        const int t = tid - 64;
        atomicAdd(&rowsum[2048 + (size_t)b * L_ + m0 + t],
                  redQ[0][t] + redQ[1][t] + redQ[2][t] + redQ[3][t]);
    }
}

// ---------------- out GEMM + inline LayerNorm: out = x + LN(loc/nf) @ out_w + out_b ----------------
__global__ __launch_bounds__(256) void k_gemm_out2(
    const float* __restrict__ loc, const float* __restrict__ rowsum,
    const float* __restrict__ outw,          // [512][512] fp32, k-major
    const float* __restrict__ lng, const float* __restrict__ lnb,
    const float* __restrict__ bias, const float* __restrict__ resid,
    float* __restrict__ out)
{
    __shared__ unsigned short As[64 * 32];
    __shared__ unsigned short Bs[64 * 32];
    __shared__ float muS[64], rsS[64], nfiS[64];
    __shared__ float lgS[512], lbS[512];
    const int tid = threadIdx.x;
    const int w = tid >> 6;
    const int lane = tid & 63;
    const int m0 = blockIdx.y * 64;
    const int n0 = blockIdx.x * 64;
    const int srow = tid >> 2;
    const int scol = (tid & 3) * 8;
    const int quad = lane >> 4, r16 = lane & 15;

    if (tid < 64) {
        const int m = m0 + tid;
        const int l = m & (L_ - 1);
        float nf = sqrtf(4.0f * (float)(l + 1));
        float rs = rowsum[m], rq = rowsum[2048 + m];
        float mu = rs / (nf * 512.0f);
        float ey2 = rq / (nf * nf * 512.0f);
        float var = ey2 - mu * mu;
        muS[tid] = mu;
        rsS[tid] = rsqrtf(var + 1e-5f);
        nfiS[tid] = 1.0f / nf;
    }
    lgS[tid] = lng[tid];       lgS[256 + tid] = lng[256 + tid];
    lbS[tid] = lnb[tid];       lbS[256 + tid] = lnb[256 + tid];
    __syncthreads();

    f32x4 acc[4];
    #pragma unroll
    for (int mt = 0; mt < 4; ++mt) acc[mt] = (f32x4){0.f, 0.f, 0.f, 0.f};

    const float* ap = loc + (size_t)(m0 + srow) * 512 + scol;
    const int tn = tid & 63;
    const int tk = tid >> 6;            // 0..3 -> kk group of 8

    for (int k0 = 0; k0 < 512; k0 += 32) {
        float4 f0 = *(const float4*)(ap + k0);
        float4 f1 = *(const float4*)(ap + k0 + 4);
        const float mu = muS[srow], rstd = rsS[srow], nfi = nfiS[srow];
        float yv[8];
        yv[0] = f0.x; yv[1] = f0.y; yv[2] = f0.z; yv[3] = f0.w;
        yv[4] = f1.x; yv[5] = f1.y; yv[6] = f1.z; yv[7] = f1.w;
        unsigned short avs[8];
        #pragma unroll
        for (int j = 0; j < 8; ++j) {
            float yn = (yv[j] * nfi - mu) * rstd * lgS[k0 + scol + j] + lbS[k0 + scol + j];
            avs[j] = f2bf(yn);
        }
        unsigned short bvs[8];
        #pragma unroll
        for (int j = 0; j < 8; ++j)
            bvs[j] = f2bf(outw[(size_t)(k0 + tk * 8 + j) * 512 + n0 + tn]);
        __syncthreads();
        *(int4*)&As[srow * 32 + scol] = *(int4*)avs;
        *(int4*)&Bs[tn * 32 + tk * 8] = *(int4*)bvs;
        __syncthreads();
        bf16x8 bfr = *(const bf16x8*)&Bs[(w * 16 + r16) * 32 + quad * 8];
        #pragma unroll
        for (int mt = 0; mt < 4; ++mt) {
            bf16x8 af = *(const bf16x8*)&As[(mt * 16 + r16) * 32 + quad * 8];
            acc[mt] = __builtin_amdgcn_mfma_f32_16x16x32_bf16(af, bfr, acc[mt], 0, 0, 0);
        }
    }
    const int n = n0 + w * 16 + r16;
    const float bn = bias[n];
    #pragma unroll
    for (int mt = 0; mt < 4; ++mt) {
        #pragma unroll
        for (int i = 0; i < 4; ++i) {
            const int m = m0 + mt * 16 + quad * 4 + i;
            out[(size_t)m * 512 + n] = acc[mt][i] + bn + resid[(size_t)m * 512 + n];
        }
    }
}

extern "C" void kernel_launch(void* const* d_in, const int* in_sizes, int n_in,
                              void* d_out, int out_size, void* d_ws, size_t ws_size,
                              hipStream_t stream)
{
    const float* x      = (const float*)d_in[0];
    const float* keyw   = (const float*)d_in[1];
    const float* qryw   = (const float*)d_in[2];
    const float* vw     = (const float*)d_in[4];
    const float* vb     = (const float*)d_in[5];
    const float* lng    = (const float*)d_in[6];
    const float* lnb    = (const float*)d_in[7];
    const float* outw   = (const float*)d_in[8];
    const float* outb   = (const float*)d_in[9];
    const float* setw   = (const float*)d_in[10];
    const float* pf     = (const float*)d_in[11];
    const float* posw   = (const float*)d_in[12];
    const float* g1w    = (const float*)d_in[13];
    const float* g1b    = (const float*)d_in[14];
    const float* g2w    = (const float*)d_in[15];
    const float* g2b    = (const float*)d_in[16];
    const float* sscale = (const float*)d_in[19];
    const float* sbias  = (const float*)d_in[20];
    const float* rscale = (const float*)d_in[21];
    const float* rthr   = (const float*)d_in[22];

    char* wsb = (char*)d_ws;
    unsigned short* Ahi  = (unsigned short*)(wsb + 0);          // 4 MiB
    unsigned short* Alo  = (unsigned short*)(wsb + 4194304);    // 4 MiB
    float*          scal = (float*)(wsb + 8388608);             // 1 MiB
    float*          loc  = (float*)(wsb + 9437184);             // 4 MiB
    float*          R    = (float*)(wsb + 13631488);            // 2.25 MiB
    unsigned short* Vthi = (unsigned short*)(wsb + 15990784);   // 2 MiB
    unsigned short* Vtlo = (unsigned short*)(wsb + 18087936);   // 2 MiB
    unsigned short* Qf   = (unsigned short*)(wsb + 20185088);   // 256 KiB
    unsigned short* Kf   = (unsigned short*)(wsb + 20447232);   // 256 KiB
    float*          gtab = (float*)(wsb + 20709376);            // 4 KiB
    float*          rowsum = (float*)(wsb + 20713472);          // 16 KiB (sum|sumsq)

    float* out = (float*)d_out;

    k_gemm1v<<<dim3(7, 32), 256, 0, stream>>>(x, keyw, qryw, g1w, vw, g1b, vb,
                                              R, Vthi, Vtlo);
    k_phasor<<<NROW / 4, 256, 0, stream>>>(R, g2w, g2b, scal);
    k_wg2<<<B_ + 1, 1024, 0, stream>>>(scal, pf, rscale, rthr, sscale, sbias,
                                       setw, gtab, Qf, Kf);
    k_buildA<<<2 * 136, 256, 0, stream>>>(Qf, Kf, scal, gtab, posw, Ahi, Alo, rowsum);
    k_av2<<<256, 256, 0, stream>>>(Ahi, Alo, Vthi, Vtlo, loc, rowsum);
    k_gemm_out2<<<dim3(8, 32), 256, 0, stream>>>(loc, rowsum, outw, lng, lnb,
                                                 outb, x, out);
}